// Round 10
// baseline (1333.375 us; speedup 1.0000x reference)
//
#include <hip/hip_runtime.h>
#include <hip/hip_cooperative_groups.h>

namespace cg = cooperative_groups;

typedef unsigned short u16;
typedef unsigned int   u32;

#define EPSBN     1e-5f
#define NEG_SLOPE 0.2f
#define NGRAPH    1024
#define NPB       512         // nodes per bucket (dst >> 9)
#define CHUNK     16384       // edges per chunk (1 << 14); NC <= 512 assumed
#define BKCAP     11264       // LDS pair capacity per bucket
#define NPASS     4           // aggregate phases; phase p = src tiles {2p,2p+1}
#define NBLK      512         // cooperative grid size (guaranteed co-resident)

static __device__ __forceinline__ float bfl(const u16* __restrict__ p, int i){
    return __uint_as_float(((u32)p[i]) << 16);
}
static __device__ __forceinline__ float ldf(const void* __restrict__ p, int i, bool f32){
    return f32 ? ((const float*)p)[i] : bfl((const u16*)p, i);
}
static __device__ __forceinline__ u16 f2bf(float f){
    u32 u = __float_as_uint(f);
    return (u16)((u + 0x7fffu + ((u >> 16) & 1u)) >> 16);
}
static __device__ __forceinline__ void unpack8(uint4 pk, float* a){
    a[0] = __uint_as_float((pk.x & 0xffffu) << 16);
    a[1] = __uint_as_float( pk.x & 0xffff0000u);
    a[2] = __uint_as_float((pk.y & 0xffffu) << 16);
    a[3] = __uint_as_float( pk.y & 0xffff0000u);
    a[4] = __uint_as_float((pk.z & 0xffffu) << 16);
    a[5] = __uint_as_float( pk.z & 0xffff0000u);
    a[6] = __uint_as_float((pk.w & 0xffffu) << 16);
    a[7] = __uint_as_float( pk.w & 0xffff0000u);
}
static __device__ __forceinline__ uint4 pack8(const float* a){
    uint4 pk;
    pk.x = (u32)f2bf(a[0]) | ((u32)f2bf(a[1])<<16);
    pk.y = (u32)f2bf(a[2]) | ((u32)f2bf(a[3])<<16);
    pk.z = (u32)f2bf(a[4]) | ((u32)f2bf(a[5])<<16);
    pk.w = (u32)f2bf(a[6]) | ((u32)f2bf(a[7])<<16);
    return pk;
}

// ---------------- dtype sniff: fp32 vs bf16 inputs ----------------
__global__ void k_sniff(const u16* __restrict__ x, int* __restrict__ flag){
    int lane = threadIdx.x;
    bool hit = false;
    for (int i = lane; i < 128; i += 64){
        float v = bfl(x, i);
        if (!(fabsf(v) <= 1e6f)) hit = true;
    }
    unsigned long long m = __ballot(hit);
    if (lane == 0) flag[0] = (m != 0ull) ? 1 : 0;
}

// ================= atomic-free radix CSR build (LDS-staged chunk sort) =================
// 1024 threads: 16 iterations/thread, 32 waves/CU at 76KB LDS (latency hiding)
__global__ __launch_bounds__(1024) void k_binsort(const int* __restrict__ src,
                                                  const int* __restrict__ dst,
                                                  u32* __restrict__ stage,
                                                  int* __restrict__ matL,
                                                  int E, int B){
    __shared__ u32 pr[CHUNK];        // 64KB: sorted pairs
    __shared__ int h[2048];          // 8KB
    __shared__ int sc[1024];         // 4KB
    int c = blockIdx.x, t = threadIdx.x;
    int e0 = c << 14, e1 = min(e0 + CHUNK, E), cn = e1 - e0;
    for (int b = t; b < B; b += 1024) h[b] = 0;
    __syncthreads();
    for (int i = e0 + t; i < e1; i += 1024) atomicAdd(&h[dst[i] >> 9], 1);
    __syncthreads();
    int base = t << 1, run = 0, loc[2];     // per = 2 (B <= 2048)
    #pragma unroll
    for (int j = 0; j < 2; j++){
        int b = base + j;
        int v = (b < B) ? h[b] : 0;
        loc[j] = run; run += v;
    }
    sc[t] = run; __syncthreads();
    for (int off = 1; off < 1024; off <<= 1){
        int x = (t >= off) ? sc[t-off] : 0;
        __syncthreads(); sc[t] += x; __syncthreads();
    }
    int bex = sc[t] - run;
    __syncthreads();
    #pragma unroll
    for (int j = 0; j < 2; j++){
        int b = base + j;
        if (b < B) h[b] = bex + loc[j];
    }
    __syncthreads();
    int* mrow = matL + (size_t)c * (B+1);
    for (int b = t; b < B; b += 1024) mrow[b] = h[b];
    if (t == 0) mrow[B] = cn;
    __syncthreads();
    for (int i = e0 + t; i < e1; i += 1024){
        int d = dst[i];
        int b = d >> 9;
        int p = atomicAdd(&h[b], 1);
        pr[p] = ((u32)src[i] << 9) | (u32)(d & 511);
    }
    __syncthreads();
    u32* srow = stage + ((size_t)c << 14);
    for (int i = t; i < cn; i += 1024) srow[i] = pr[i];
}

// tiled transpose: matL[NC][B+1] -> matT[B+1][NC]
__global__ __launch_bounds__(256) void k_mtrans(const int* __restrict__ matL,
                                                int* __restrict__ matT, int R, int C){
    __shared__ int tile[32][33];
    int tx = threadIdx.x & 31, ty = threadIdx.x >> 5;   // 32x8
    int c0 = blockIdx.x << 5, r0 = blockIdx.y << 5;
    for (int j = ty; j < 32; j += 8){
        int r = r0 + j, c = c0 + tx;
        if (r < C && c < R) tile[j][tx] = matL[(size_t)r*R + c];
    }
    __syncthreads();
    for (int j = ty; j < 32; j += 8){
        int cc = c0 + j, rr = r0 + tx;
        if (cc < R && rr < C) matT[(size_t)cc*C + rr] = tile[tx][j];
    }
}

__global__ __launch_bounds__(256) void k_bucketsum(const int* __restrict__ matT,
                                                   int* __restrict__ bb, int B, int NC){
    int b = blockIdx.x, t = threadIdx.x;
    __shared__ int s[256];
    int acc = 0;
    const int* r0 = matT + (size_t)b*NC;
    const int* r1 = matT + (size_t)(b+1)*NC;
    for (int c = t; c < NC; c += 256) acc += r1[c] - r0[c];
    s[t] = acc; __syncthreads();
    for (int off = 128; off > 0; off >>= 1){
        if (t < off) s[t] += s[t+off];
        __syncthreads();
    }
    if (t == 0) bb[b] = s[0];
}

__global__ __launch_bounds__(1024) void k_bktbase(int* __restrict__ bb, int B){
    __shared__ int s[1024];
    int t = threadIdx.x;
    int v = (t < B) ? bb[t] : 0;
    s[t] = v; __syncthreads();
    for (int off = 1; off < 1024; off <<= 1){
        int x = (t >= off) ? s[t-off] : 0;
        __syncthreads();
        s[t] += x;
        __syncthreads();
    }
    if (t < B) bb[t] = s[t] - v;
    if (t == B-1) bb[B] = s[t];
}

// per-bucket: coalesced binary-search gather, counting-sort by (dstLocal, srcTile),
// emit row8T (pass-major int2 lo/hi) and csr.
__global__ __launch_bounds__(512) void k_bucket(const u32* __restrict__ stage,
                                                const int* __restrict__ matT,
                                                const int* __restrict__ bb,
                                                int2* __restrict__ row8T,
                                                int* __restrict__ csr,
                                                int N, int B, int NC, int M){
    __shared__ u32 pr[BKCAP];        // 44KB
    __shared__ int hist[4096];       // 16KB
    __shared__ int sc[512];          // 2KB
    __shared__ int lofsA[512];       // 2KB
    int k = blockIdx.x, t = threadIdx.x;
    int n0 = k << 9, n1 = min(n0 + NPB, N), nn = n1 - n0;
    int cnt = 0, lofs = 0;
    if (t < NC){
        lofs = matT[(size_t)k*NC + t];
        cnt  = matT[(size_t)(k+1)*NC + t] - lofs;
    }
    lofsA[t] = lofs;
    sc[t] = cnt; __syncthreads();
    for (int off = 1; off < 512; off <<= 1){
        int x = (t >= off) ? sc[t-off] : 0;
        __syncthreads(); sc[t] += x; __syncthreads();
    }
    int total = sc[511];
    int ec    = min(total, BKCAP - nn);
    for (int pidx = t; pidx < ec; pidx += 512){
        int lo = 0, hi = 511;
        while (lo < hi){ int mid = (lo + hi) >> 1; if (sc[mid] > pidx) hi = mid; else lo = mid + 1; }
        int segStart = lo ? sc[lo-1] : 0;
        pr[pidx] = stage[((size_t)lo << 14) + lofsA[lo] + (pidx - segStart)];
    }
    __syncthreads();
    for (int j = t; j < nn; j += 512) pr[ec + j] = ((u32)(n0 + j) << 9) | (u32)j;  // self-loops
    int ecnt = ec + nn;
    for (int i = t; i < 4096; i += 512) hist[i] = 0;
    __syncthreads();
    for (int i = t; i < ecnt; i += 512){
        u32 pk = pr[i];
        int dl = pk & 511;
        int tile = min((int)(pk >> 9) >> 16, 7);
        atomicAdd(&hist[(dl << 3) + tile], 1);
    }
    __syncthreads();
    int base = t << 3, run = 0, loc[8];
    #pragma unroll
    for (int j = 0; j < 8; j++){ loc[j] = run; run += hist[base + j]; }
    sc[t] = run; __syncthreads();
    for (int off = 1; off < 512; off <<= 1){
        int x = (t >= off) ? sc[t-off] : 0;
        __syncthreads();
        sc[t] += x;
        __syncthreads();
    }
    int bex = sc[t] - run;          // exclusive; sc[t] = inclusive (node end)
    __syncthreads();
    #pragma unroll
    for (int j = 0; j < 8; j++) hist[base + j] = bex + loc[j];
    __syncthreads();
    int wbase = bb[k] + n0;
    if (t < nn){
        int i = n0 + t;
        int nodeEnd = wbase + sc[t];
        #pragma unroll
        for (int p2 = 0; p2 < NPASS; p2++){
            int st = wbase + hist[(t << 3) + 2*p2];
            int en = (p2 == NPASS-1) ? nodeEnd : wbase + hist[(t << 3) + 2*p2 + 2];
            row8T[(size_t)p2*N + i] = make_int2(st, en);
        }
    }
    __syncthreads();
    for (int i = t; i < ecnt; i += 512){
        u32 pk = pr[i];
        int dl = pk & 511;
        int s  = (int)(pk >> 9);
        int tile = min(s >> 9 >> 7, 7) > 7 ? 7 : min(s >> 16, 7);
        int p = atomicAdd(&hist[(dl << 3) + tile], 1);
        csr[wbase + p] = s;
    }
    (void)M;
}

// ---------------- node transform (+ fused BN/PReLU of previous layer) ----------------
__global__ void k_transform(const uint4* __restrict__ actpk, const void* __restrict__ xraw,
                            const int* __restrict__ dflag, int fin,
                            const void* __restrict__ W, const void* __restrict__ adst,
                            const float* __restrict__ stats, const void* __restrict__ gamma,
                            const void* __restrict__ beta, const void* __restrict__ alpha,
                            uint4* __restrict__ hrec, float* __restrict__ hd, int n){
    const bool f32 = dflag[0] != 0;
    __shared__ float Wl[64], dl[8], scl[8], sft[8], alv;
    int t = threadIdx.x;
    if (t < 64)            Wl[t]   = (t < fin*8) ? ldf(W, t, f32) : 0.f;
    if (t >= 64 && t < 72) dl[t-64] = ldf(adst, t-64, f32);
    if (t == 80) alv = ldf(alpha, 0, f32);
    if (stats && t < 8){
        float invN = 1.f/(float)n;
        float mu  = stats[t]*invN;
        float var = fmaxf(stats[8+t]*invN - mu*mu, 0.f);
        float s   = ldf(gamma, t, f32)*rsqrtf(var + EPSBN);
        scl[t] = s; sft[t] = ldf(beta, t, f32) - mu*s;
    }
    __syncthreads();
    int i = blockIdx.x*blockDim.x + t;
    if (i >= n) return;
    float a[8];
    if (xraw){
        #pragma unroll
        for (int k=0;k<7;k++) a[k] = ldf(xraw, i*7 + k, f32);
        a[7] = 0.f;
    } else {
        unpack8(actpk[i], a);
        #pragma unroll
        for (int j=0;j<8;j++){
            float y = a[j]*scl[j] + sft[j];
            a[j] = (y > 0.f) ? y : alv*y;
        }
    }
    float h[8];
    #pragma unroll
    for (int j=0;j<8;j++){
        float acc = 0.f;
        #pragma unroll
        for (int k=0;k<8;k++) acc += a[k]*Wl[k*8+j];
        h[j] = acc;
    }
    float s2 = 0.f;
    #pragma unroll
    for (int j=0;j<8;j++) s2 += h[j]*dl[j];
    hd[i] = s2;
    hrec[i] = pack8(h);
}

// ---------------- cooperative fused GAT aggregation: 4 tile-phases, state in LDS ------
__global__ __launch_bounds__(512, 4) void k_gatcoop(
        const int2* __restrict__ row8T, const int* __restrict__ csr,
        const uint4* __restrict__ hrec, const float* __restrict__ hd,
        const void* __restrict__ asrc, const int* __restrict__ dflag,
        uint4* __restrict__ act, float* __restrict__ partials, int n, int ngroups){
    cg::grid_group grid = cg::this_grid();
    const bool f32 = dflag[0] != 0;
    __shared__ float accL[2][512][9];    // 36KB: 8 acc + den per node
    __shared__ float hdL[2][512];        // 4KB
    __shared__ float al[8];
    __shared__ float sred[8][16];
    int t = threadIdx.x, blk = blockIdx.x;
    if (t < 8) al[t] = ldf(asrc, t, f32);
    #pragma unroll
    for (int g = 0; g < 2; g++){
        int gid = g*NBLK + blk;
        int i = gid*512 + t;
        if (gid < ngroups && i < n) hdL[g][t] = hd[i];
        #pragma unroll
        for (int j = 0; j < 9; j++) accL[g][t][j] = 0.f;
    }
    __syncthreads();
    for (int ps = 0; ps < NPASS; ps++){
        const bool last = (ps == NPASS-1);
        for (int g = 0; g < 2; g++){
            int gid = g*NBLK + blk;
            int i = gid*512 + t;
            float o[8] = {0,0,0,0,0,0,0,0};
            bool active = (gid < ngroups) && (i < n);
            if (active){
                int2 lh = row8T[(size_t)ps*n + i];
                float hdv = hdL[g][t];
                float acc[8], den;
                #pragma unroll
                for (int j = 0; j < 8; j++) acc[j] = accL[g][t][j];
                den = accL[g][t][8];
                for (int p = lh.x; p < lh.y; ++p){
                    int s = csr[p];
                    uint4 pk = hrec[s];
                    float hv[8];
                    unpack8(pk, hv);
                    float e = hdv;
                    #pragma unroll
                    for (int j = 0; j < 8; j++) e += hv[j]*al[j];
                    e = (e > 0.f) ? e : NEG_SLOPE*e;
                    float w = __expf(e);
                    den += w;
                    #pragma unroll
                    for (int j = 0; j < 8; j++) acc[j] += w*hv[j];
                }
                if (!last){
                    #pragma unroll
                    for (int j = 0; j < 8; j++) accL[g][t][j] = acc[j];
                    accL[g][t][8] = den;
                } else {
                    float inv = 1.f / (den + 1e-16f);
                    #pragma unroll
                    for (int j = 0; j < 8; j++) o[j] = acc[j]*inv;
                    act[i] = pack8(o);
                }
            }
            if (last){
                // BN stats partials for this group (o = 0 for inactive threads)
                float v[16];
                #pragma unroll
                for (int j = 0; j < 8; j++){ v[j] = o[j]; v[8+j] = o[j]*o[j]; }
                #pragma unroll
                for (int off = 32; off > 0; off >>= 1){
                    #pragma unroll
                    for (int j = 0; j < 16; j++) v[j] += __shfl_down(v[j], off, 64);
                }
                int lane = t & 63, wv = t >> 6;
                if (lane == 0){
                    #pragma unroll
                    for (int j = 0; j < 16; j++) sred[wv][j] = v[j];
                }
                __syncthreads();
                if (t < 16 && gid < ngroups){
                    float tot = 0.f;
                    #pragma unroll
                    for (int w = 0; w < 8; w++) tot += sred[w][t];
                    partials[(size_t)gid*16 + t] = tot;
                }
                __syncthreads();
            }
        }
        if (!last) grid.sync();
    }
}

__global__ void k_statreduce(const float* __restrict__ partials, float* __restrict__ stats, int nb){
    __shared__ float s[256];
    int t = threadIdx.x;
    int col = t & 15, rg = t >> 4;
    float acc = 0.f;
    for (int r = rg; r < nb; r += 16) acc += partials[(size_t)r*16 + col];
    s[t] = acc; __syncthreads();
    if (t < 16){
        float tot = 0.f;
        #pragma unroll
        for (int k=0;k<16;k++) tot += s[k*16 + t];
        stats[t] = tot;
    }
}

// ---------------- JK-cat (BN+PReLU fused) @ Wjk + bjk, pooled per graph ----------------
static __device__ __forceinline__ int lowerb(const int* __restrict__ a, int n, int key){
    int lo = 0, hi = n;
    while (lo < hi){ int mid = (lo + hi) >> 1; if (a[mid] < key) lo = mid + 1; else hi = mid; }
    return lo;
}

__global__ __launch_bounds__(256) void k_jkpool(
        const uint4* __restrict__ a1, const uint4* __restrict__ a2, const uint4* __restrict__ a3,
        const float* __restrict__ st1, const float* __restrict__ st2, const float* __restrict__ st3,
        const void* __restrict__ g1, const void* __restrict__ be1,
        const void* __restrict__ g2, const void* __restrict__ be2,
        const void* __restrict__ g3, const void* __restrict__ be3,
        const void* __restrict__ alpha,
        const void* __restrict__ Wjk, const void* __restrict__ bjk,
        const int* __restrict__ dflag,
        const int* __restrict__ batch, float* __restrict__ pooled, int n){
    const bool f32 = dflag[0] != 0;
    __shared__ float Wl[192], bl[8], scl[24], sft[24], alv;
    __shared__ int rng[2];
    int t = threadIdx.x, g = blockIdx.x;
    if (t < 192) Wl[t] = ldf(Wjk, t, f32);
    if (t < 8)   bl[t] = ldf(bjk, t, f32);
    if (t < 24){
        int L = t >> 3, j = t & 7;
        const float* st = (L==0)? st1 : (L==1)? st2 : st3;
        const void* gg  = (L==0)? g1  : (L==1)? g2  : g3;
        const void* bb_ = (L==0)? be1 : (L==1)? be2 : be3;
        float invN = 1.f/(float)n;
        float mu  = st[j]*invN;
        float var = fmaxf(st[8+j]*invN - mu*mu, 0.f);
        float s   = ldf(gg, j, f32)*rsqrtf(var + EPSBN);
        scl[t] = s; sft[t] = ldf(bb_, j, f32) - mu*s;
    }
    if (t == 30) alv = ldf(alpha, 0, f32);
    if (t == 0) rng[0] = lowerb(batch, n, g);
    if (t == 1) rng[1] = lowerb(batch, n, g+1);
    __syncthreads();
    int lo = rng[0], hi = rng[1];
    float pa[8] = {0,0,0,0,0,0,0,0};
    for (int i = lo + t; i < hi; i += 256){
        float c[24];
        unpack8(a1[i], c);
        unpack8(a2[i], c+8);
        unpack8(a3[i], c+16);
        #pragma unroll
        for (int k=0;k<24;k++){
            float y = c[k]*scl[k] + sft[k];
            c[k] = (y > 0.f) ? y : alv*y;
        }
        #pragma unroll
        for (int j=0;j<8;j++){
            float acc = bl[j];
            #pragma unroll
            for (int k=0;k<24;k++) acc += c[k]*Wl[k*8+j];
            pa[j] += acc;
        }
    }
    #pragma unroll
    for (int off=32; off>0; off>>=1){
        #pragma unroll
        for (int j=0;j<8;j++) pa[j] += __shfl_down(pa[j], off, 64);
    }
    __shared__ float sr[4][8];
    int lane = t & 63, wv = t >> 6;
    if (lane == 0){
        #pragma unroll
        for (int j=0;j<8;j++) sr[wv][j] = pa[j];
    }
    __syncthreads();
    if (t < 8){
        float tot = sr[0][t]+sr[1][t]+sr[2][t]+sr[3][t];
        pooled[(size_t)g*8 + t] = tot;
    }
}

// ---------------- MLP head ----------------
__global__ __launch_bounds__(1024) void k_final(
        const float* __restrict__ pooled,
        const void* __restrict__ Wm1, const void* __restrict__ bm1,
        const void* __restrict__ gm, const void* __restrict__ bem,
        const void* __restrict__ am,
        const void* __restrict__ Wm2, const void* __restrict__ bm2,
        const int* __restrict__ dflag,
        float* __restrict__ out, int G){
    const bool f32 = dflag[0] != 0;
    int t = threadIdx.x;
    float tv[8] = {0,0,0,0,0,0,0,0};
    if (t < G){
        float r[8];
        #pragma unroll
        for (int j=0;j<8;j++) r[j] = pooled[(size_t)t*8+j];
        #pragma unroll
        for (int j=0;j<8;j++){
            float acc = ldf(bm1, j, f32);
            #pragma unroll
            for (int k=0;k<8;k++) acc += r[k]*ldf(Wm1, k*8+j, f32);
            tv[j] = acc;
        }
    }
    float v[16];
    #pragma unroll
    for (int j=0;j<8;j++){ v[j]=tv[j]; v[8+j]=tv[j]*tv[j]; }
    #pragma unroll
    for (int off=32; off>0; off>>=1){
        #pragma unroll
        for (int j=0;j<16;j++) v[j] += __shfl_down(v[j], off, 64);
    }
    __shared__ float sred[16][16];
    int lane = t & 63, wv = t >> 6;
    if (lane == 0){
        #pragma unroll
        for (int j=0;j<16;j++) sred[wv][j] = v[j];
    }
    __syncthreads();
    __shared__ float stt[16];
    if (t < 16){
        float tot = 0.f;
        #pragma unroll
        for (int w=0; w<16; w++) tot += sred[w][t];
        stt[t] = tot;
    }
    __syncthreads();
    if (t < G){
        float a = ldf(am, 0, f32);
        float invG = 1.f/(float)G;
        float m1[8];
        #pragma unroll
        for (int j=0;j<8;j++){
            float mu  = stt[j]*invG;
            float var = fmaxf(stt[8+j]*invG - mu*mu, 0.f);
            float y = (tv[j]-mu)*rsqrtf(var+EPSBN)*ldf(gm,j,f32)+ldf(bem,j,f32);
            m1[j] = (y>0.f)? y : a*y;
        }
        #pragma unroll
        for (int c=0;c<2;c++){
            float oacc = ldf(bm2, c, f32);
            #pragma unroll
            for (int k=0;k<8;k++) oacc += m1[k]*ldf(Wm2, k*2+c, f32);
            out[(size_t)t*2+c] = oacc;
        }
    }
}

extern "C" void kernel_launch(void* const* d_in, const int* in_sizes, int n_in,
                              void* d_out, int out_size, void* d_ws, size_t ws_size,
                              hipStream_t stream){
    const u16* x16   = (const u16*)d_in[0];
    const void* x    = d_in[0];
    const int* ei    = (const int*)d_in[1];
    const int* batch = (const int*)d_in[2];
    int N = in_sizes[2];
    int E = in_sizes[1] / 2;
    const int* srcA = ei;
    const int* dstA = ei + E;
    const void *W1=d_in[3],  *as1=d_in[4],  *ad1=d_in[5];
    const void *W2=d_in[7],  *as2=d_in[8],  *ad2=d_in[9];
    const void *W3=d_in[11], *as3=d_in[12], *ad3=d_in[13];
    const void *g1=d_in[15], *be1=d_in[16];
    const void *g2=d_in[17], *be2=d_in[18];
    const void *g3=d_in[19], *be3=d_in[20];
    const void *agnn=d_in[21];
    const void *Wjk=d_in[22], *bjk=d_in[23];
    const void *Wm1=d_in[24], *bm1=d_in[25];
    const void *gm =d_in[26], *bem=d_in[27];
    const void *amlp=d_in[28];
    const void *Wm2=d_in[29], *bm2=d_in[30];

    char* p = (char*)d_ws;
    auto carve = [&](size_t bytes) -> void* {
        void* r = (void*)p;
        p += (bytes + 255) & ~(size_t)255;
        return r;
    };
    size_t M = (size_t)E + (size_t)N;
    int nb512 = (N + 511)/512;                 // = ngroups
    int B  = (N + NPB - 1) / NPB;
    int NC = (E + CHUNK - 1) / CHUNK;          // <= 512
    int*   dflag  = (int*)  carve(256);
    int2*  row8T  = (int2*) carve((size_t)NPASS*N*8);
    int*   bb     = (int*)  carve(((size_t)B+1)*4);
    int*   matL   = (int*)  carve((size_t)NC*(B+1)*4);
    int*   matT   = (int*)  carve((size_t)(B+1)*NC*4);
    u32*   stage  = (u32*)  carve((size_t)NC*CHUNK*4);
    int*   csr    = (int*)  carve(M*4);
    uint4* hrec   = (uint4*)carve((size_t)N*16);
    float* hd     = (float*)carve((size_t)N*4);
    uint4* act1   = (uint4*)carve((size_t)N*16);
    uint4* act2   = (uint4*)carve((size_t)N*16);
    uint4* act3   = (uint4*)carve((size_t)N*16);
    float* parts  = (float*)carve((size_t)nb512*64);
    float* stats1 = (float*)carve(64);
    float* stats2 = (float*)carve(64);
    float* stats3 = (float*)carve(64);
    float* pooled = (float*)carve((size_t)NGRAPH*32);
    (void)ws_size; (void)n_in;

    k_sniff<<<1, 64, 0, stream>>>(x16, dflag);

    // ---- atomic-free radix CSR build ----
    k_binsort  <<<NC, 1024, 0, stream>>>(srcA, dstA, stage, matL, E, B);
    {
        dim3 tg(((B+1) + 31)/32, (NC + 31)/32);
        k_mtrans<<<tg, 256, 0, stream>>>(matL, matT, B+1, NC);
    }
    k_bucketsum<<<B, 256, 0, stream>>>(matT, bb, B, NC);
    k_bktbase  <<<1, 1024, 0, stream>>>(bb, B);
    k_bucket   <<<B, 512, 0, stream>>>(stage, matT, bb, row8T, csr, N, B, NC, (int)M);

    int ngroups = nb512;
    auto coop = [&](const void* as, uint4* act){
        void* args[] = { (void*)&row8T, (void*)&csr, (void*)&hrec, (void*)&hd,
                         (void*)&as, (void*)&dflag, (void*)&act, (void*)&parts,
                         (void*)&N, (void*)&ngroups };
        hipLaunchCooperativeKernel((const void*)k_gatcoop, dim3(NBLK), dim3(512),
                                   args, 0, stream);
    };

    // layer 1
    k_transform <<<nb512, 512, 0, stream>>>(nullptr, x, dflag, 7, W1, ad1,
                                            nullptr, nullptr, nullptr, agnn, hrec, hd, N);
    coop(as1, act1);
    k_statreduce<<<1, 256, 0, stream>>>(parts, stats1, nb512);
    // layer 2 (BN1+PReLU fused into transform)
    k_transform <<<nb512, 512, 0, stream>>>(act1, nullptr, dflag, 8, W2, ad2,
                                            stats1, g1, be1, agnn, hrec, hd, N);
    coop(as2, act2);
    k_statreduce<<<1, 256, 0, stream>>>(parts, stats2, nb512);
    // layer 3
    k_transform <<<nb512, 512, 0, stream>>>(act2, nullptr, dflag, 8, W3, ad3,
                                            stats2, g2, be2, agnn, hrec, hd, N);
    coop(as3, act3);
    k_statreduce<<<1, 256, 0, stream>>>(parts, stats3, nb512);

    // JK (BN+PReLU fused) + pool + head
    k_jkpool<<<NGRAPH, 256, 0, stream>>>(act1, act2, act3, stats1, stats2, stats3,
                                         g1, be1, g2, be2, g3, be3, agnn,
                                         Wjk, bjk, dflag, batch, pooled, N);
    int G = out_size / 2;
    k_final <<<1, 1024, 0, stream>>>(pooled, Wm1, bm1, gm, bem, amlp, Wm2, bm2, dflag, (float*)d_out, G);
}

// Round 11
// 690.255 us; speedup vs baseline: 1.9317x; 1.9317x over previous
//
#include <hip/hip_runtime.h>

typedef unsigned short u16;
typedef unsigned int   u32;

#define EPSBN     1e-5f
#define NEG_SLOPE 0.2f
#define NGRAPH    1024
#define NPB       512         // nodes per bucket (dst >> 9)
#define CHUNK     16384       // edges per chunk (1 << 14); NC <= 512 assumed
#define BKCAP     11264       // LDS pair capacity per bucket

static __device__ __forceinline__ float bfl(const u16* __restrict__ p, int i){
    return __uint_as_float(((u32)p[i]) << 16);
}
static __device__ __forceinline__ float ldf(const void* __restrict__ p, int i, bool f32){
    return f32 ? ((const float*)p)[i] : bfl((const u16*)p, i);
}
static __device__ __forceinline__ u16 f2bf(float f){
    u32 u = __float_as_uint(f);
    return (u16)((u + 0x7fffu + ((u >> 16) & 1u)) >> 16);
}
static __device__ __forceinline__ void unpack8(uint4 pk, float* a){
    a[0] = __uint_as_float((pk.x & 0xffffu) << 16);
    a[1] = __uint_as_float( pk.x & 0xffff0000u);
    a[2] = __uint_as_float((pk.y & 0xffffu) << 16);
    a[3] = __uint_as_float( pk.y & 0xffff0000u);
    a[4] = __uint_as_float((pk.z & 0xffffu) << 16);
    a[5] = __uint_as_float( pk.z & 0xffff0000u);
    a[6] = __uint_as_float((pk.w & 0xffffu) << 16);
    a[7] = __uint_as_float( pk.w & 0xffff0000u);
}
static __device__ __forceinline__ uint4 pack8(const float* a){
    uint4 pk;
    pk.x = (u32)f2bf(a[0]) | ((u32)f2bf(a[1])<<16);
    pk.y = (u32)f2bf(a[2]) | ((u32)f2bf(a[3])<<16);
    pk.z = (u32)f2bf(a[4]) | ((u32)f2bf(a[5])<<16);
    pk.w = (u32)f2bf(a[6]) | ((u32)f2bf(a[7])<<16);
    return pk;
}
// one edge: unpack hrec, attention weight, accumulate
static __device__ __forceinline__ void edge_acc(uint4 pk, float hdv,
                                                const float* __restrict__ al,
                                                float* acc, float& den){
    float hv[8];
    unpack8(pk, hv);
    float e = hdv;
    #pragma unroll
    for (int j = 0; j < 8; j++) e += hv[j]*al[j];
    e = (e > 0.f) ? e : NEG_SLOPE*e;
    float w = __expf(e);
    den += w;
    #pragma unroll
    for (int j = 0; j < 8; j++) acc[j] += w*hv[j];
}

// ---------------- dtype sniff: fp32 vs bf16 inputs ----------------
__global__ void k_sniff(const u16* __restrict__ x, int* __restrict__ flag){
    int lane = threadIdx.x;
    bool hit = false;
    for (int i = lane; i < 128; i += 64){
        float v = bfl(x, i);
        if (!(fabsf(v) <= 1e6f)) hit = true;
    }
    unsigned long long m = __ballot(hit);
    if (lane == 0) flag[0] = (m != 0ull) ? 1 : 0;
}

// ================= atomic-free radix CSR build (LDS-staged chunk sort) =================
__global__ __launch_bounds__(1024) void k_binsort(const int* __restrict__ src,
                                                  const int* __restrict__ dst,
                                                  u32* __restrict__ stage,
                                                  int* __restrict__ matL,
                                                  int E, int B){
    __shared__ u32 pr[CHUNK];        // 64KB: sorted pairs
    __shared__ int h[2048];          // 8KB
    __shared__ int sc[1024];         // 4KB
    int c = blockIdx.x, t = threadIdx.x;
    int e0 = c << 14, e1 = min(e0 + CHUNK, E), cn = e1 - e0;
    for (int b = t; b < B; b += 1024) h[b] = 0;
    __syncthreads();
    for (int i = e0 + t; i < e1; i += 1024) atomicAdd(&h[dst[i] >> 9], 1);
    __syncthreads();
    int base = t << 1, run = 0, loc[2];     // per = 2 (B <= 2048)
    #pragma unroll
    for (int j = 0; j < 2; j++){
        int b = base + j;
        int v = (b < B) ? h[b] : 0;
        loc[j] = run; run += v;
    }
    sc[t] = run; __syncthreads();
    for (int off = 1; off < 1024; off <<= 1){
        int x = (t >= off) ? sc[t-off] : 0;
        __syncthreads(); sc[t] += x; __syncthreads();
    }
    int bex = sc[t] - run;
    __syncthreads();
    #pragma unroll
    for (int j = 0; j < 2; j++){
        int b = base + j;
        if (b < B) h[b] = bex + loc[j];
    }
    __syncthreads();
    int* mrow = matL + (size_t)c * (B+1);
    for (int b = t; b < B; b += 1024) mrow[b] = h[b];
    if (t == 0) mrow[B] = cn;
    __syncthreads();
    for (int i = e0 + t; i < e1; i += 1024){
        int d = dst[i];
        int b = d >> 9;
        int p = atomicAdd(&h[b], 1);
        pr[p] = ((u32)src[i] << 9) | (u32)(d & 511);
    }
    __syncthreads();
    u32* srow = stage + ((size_t)c << 14);
    for (int i = t; i < cn; i += 1024) srow[i] = pr[i];
}

// tiled transpose: matL[NC][B+1] -> matT[B+1][NC]
__global__ __launch_bounds__(256) void k_mtrans(const int* __restrict__ matL,
                                                int* __restrict__ matT, int R, int C){
    __shared__ int tile[32][33];
    int tx = threadIdx.x & 31, ty = threadIdx.x >> 5;   // 32x8
    int c0 = blockIdx.x << 5, r0 = blockIdx.y << 5;
    for (int j = ty; j < 32; j += 8){
        int r = r0 + j, c = c0 + tx;
        if (r < C && c < R) tile[j][tx] = matL[(size_t)r*R + c];
    }
    __syncthreads();
    for (int j = ty; j < 32; j += 8){
        int cc = c0 + j, rr = r0 + tx;
        if (cc < R && rr < C) matT[(size_t)cc*C + rr] = tile[tx][j];
    }
}

__global__ __launch_bounds__(256) void k_bucketsum(const int* __restrict__ matT,
                                                   int* __restrict__ bb, int B, int NC){
    int b = blockIdx.x, t = threadIdx.x;
    __shared__ int s[256];
    int acc = 0;
    const int* r0 = matT + (size_t)b*NC;
    const int* r1 = matT + (size_t)(b+1)*NC;
    for (int c = t; c < NC; c += 256) acc += r1[c] - r0[c];
    s[t] = acc; __syncthreads();
    for (int off = 128; off > 0; off >>= 1){
        if (t < off) s[t] += s[t+off];
        __syncthreads();
    }
    if (t == 0) bb[b] = s[0];
}

__global__ __launch_bounds__(1024) void k_bktbase(int* __restrict__ bb, int B){
    __shared__ int s[1024];
    int t = threadIdx.x;
    int v = (t < B) ? bb[t] : 0;
    s[t] = v; __syncthreads();
    for (int off = 1; off < 1024; off <<= 1){
        int x = (t >= off) ? s[t-off] : 0;
        __syncthreads();
        s[t] += x;
        __syncthreads();
    }
    if (t < B) bb[t] = s[t] - v;
    if (t == B-1) bb[B] = s[t];
}

// per-bucket: coalesced binary-search gather, counting-sort by (dstLocal, srcTile),
// emit rowSE (int2 lo/hi per node) and csr (rows internally sorted by src tile).
__global__ __launch_bounds__(512) void k_bucket(const u32* __restrict__ stage,
                                                const int* __restrict__ matT,
                                                const int* __restrict__ bb,
                                                int2* __restrict__ rowSE,
                                                int* __restrict__ csr,
                                                int N, int B, int NC){
    __shared__ u32 pr[BKCAP];        // 44KB
    __shared__ int hist[4096];       // 16KB
    __shared__ int sc[512];          // 2KB
    __shared__ int lofsA[512];       // 2KB
    int k = blockIdx.x, t = threadIdx.x;
    int n0 = k << 9, n1 = min(n0 + NPB, N), nn = n1 - n0;
    int cnt = 0, lofs = 0;
    if (t < NC){
        lofs = matT[(size_t)k*NC + t];
        cnt  = matT[(size_t)(k+1)*NC + t] - lofs;
    }
    lofsA[t] = lofs;
    sc[t] = cnt; __syncthreads();
    for (int off = 1; off < 512; off <<= 1){
        int x = (t >= off) ? sc[t-off] : 0;
        __syncthreads(); sc[t] += x; __syncthreads();
    }
    int total = sc[511];
    int ec    = min(total, BKCAP - nn);
    for (int pidx = t; pidx < ec; pidx += 512){
        int lo = 0, hi = 511;
        while (lo < hi){ int mid = (lo + hi) >> 1; if (sc[mid] > pidx) hi = mid; else lo = mid + 1; }
        int segStart = lo ? sc[lo-1] : 0;
        pr[pidx] = stage[((size_t)lo << 14) + lofsA[lo] + (pidx - segStart)];
    }
    __syncthreads();
    for (int j = t; j < nn; j += 512) pr[ec + j] = ((u32)(n0 + j) << 9) | (u32)j;  // self-loops
    int ecnt = ec + nn;
    for (int i = t; i < 4096; i += 512) hist[i] = 0;
    __syncthreads();
    for (int i = t; i < ecnt; i += 512){
        u32 pk = pr[i];
        int dl = pk & 511;
        int tile = min((int)(pk >> 9) >> 16, 7);
        atomicAdd(&hist[(dl << 3) + tile], 1);
    }
    __syncthreads();
    int base = t << 3, run = 0, loc[8];
    #pragma unroll
    for (int j = 0; j < 8; j++){ loc[j] = run; run += hist[base + j]; }
    sc[t] = run; __syncthreads();
    for (int off = 1; off < 512; off <<= 1){
        int x = (t >= off) ? sc[t-off] : 0;
        __syncthreads();
        sc[t] += x;
        __syncthreads();
    }
    int bex = sc[t] - run;          // exclusive; sc[t] = inclusive (node end)
    __syncthreads();
    #pragma unroll
    for (int j = 0; j < 8; j++) hist[base + j] = bex + loc[j];
    __syncthreads();
    int wbase = bb[k] + n0;
    if (t < nn){
        rowSE[n0 + t] = make_int2(wbase + hist[t << 3], wbase + sc[t]);
    }
    __syncthreads();
    for (int i = t; i < ecnt; i += 512){
        u32 pk = pr[i];
        int dl = pk & 511;
        int s  = (int)(pk >> 9);
        int tile = min(s >> 16, 7);
        int p = atomicAdd(&hist[(dl << 3) + tile], 1);
        csr[wbase + p] = s;
    }
}

// ---------------- node transform (+ fused BN/PReLU of previous layer) ----------------
__global__ void k_transform(const uint4* __restrict__ actpk, const void* __restrict__ xraw,
                            const int* __restrict__ dflag, int fin,
                            const void* __restrict__ W, const void* __restrict__ adst,
                            const float* __restrict__ stats, const void* __restrict__ gamma,
                            const void* __restrict__ beta, const void* __restrict__ alpha,
                            uint4* __restrict__ hrec, float* __restrict__ hd, int n){
    const bool f32 = dflag[0] != 0;
    __shared__ float Wl[64], dl[8], scl[8], sft[8], alv;
    int t = threadIdx.x;
    if (t < 64)            Wl[t]   = (t < fin*8) ? ldf(W, t, f32) : 0.f;
    if (t >= 64 && t < 72) dl[t-64] = ldf(adst, t-64, f32);
    if (t == 80) alv = ldf(alpha, 0, f32);
    if (stats && t < 8){
        float invN = 1.f/(float)n;
        float mu  = stats[t]*invN;
        float var = fmaxf(stats[8+t]*invN - mu*mu, 0.f);
        float s   = ldf(gamma, t, f32)*rsqrtf(var + EPSBN);
        scl[t] = s; sft[t] = ldf(beta, t, f32) - mu*s;
    }
    __syncthreads();
    int i = blockIdx.x*blockDim.x + t;
    if (i >= n) return;
    float a[8];
    if (xraw){
        #pragma unroll
        for (int k=0;k<7;k++) a[k] = ldf(xraw, i*7 + k, f32);
        a[7] = 0.f;
    } else {
        unpack8(actpk[i], a);
        #pragma unroll
        for (int j=0;j<8;j++){
            float y = a[j]*scl[j] + sft[j];
            a[j] = (y > 0.f) ? y : alv*y;
        }
    }
    float h[8];
    #pragma unroll
    for (int j=0;j<8;j++){
        float acc = 0.f;
        #pragma unroll
        for (int k=0;k<8;k++) acc += a[k]*Wl[k*8+j];
        h[j] = acc;
    }
    float s2 = 0.f;
    #pragma unroll
    for (int j=0;j<8;j++) s2 += h[j]*dl[j];
    hd[i] = s2;
    hrec[i] = pack8(h);
}

// ---------------- GAT aggregate: single pass, 4-wide batched gathers (MLP=4) ----------
__global__ __launch_bounds__(512) void k_aggregate(
        const int2* __restrict__ rowSE, const int* __restrict__ csr,
        const uint4* __restrict__ hrec, const float* __restrict__ hd,
        const void* __restrict__ asrc, const int* __restrict__ dflag,
        uint4* __restrict__ act, float* __restrict__ partials, int n){
    const bool f32 = dflag[0] != 0;
    __shared__ float al[8];
    int t = threadIdx.x;
    if (t < 8) al[t] = ldf(asrc, t, f32);
    __syncthreads();
    float alr[8];
    #pragma unroll
    for (int j = 0; j < 8; j++) alr[j] = al[j];
    int i = blockIdx.x*512 + t;
    float o[8] = {0,0,0,0,0,0,0,0};
    if (i < n){
        int2 lh = rowSE[i];
        float hdv = hd[i];
        float den = 0.f;
        float acc[8] = {0,0,0,0,0,0,0,0};
        int p = lh.x;
        // 4-wide: 4 independent gathers in flight per iteration
        for (; p + 4 <= lh.y; p += 4){
            int s0 = csr[p], s1 = csr[p+1], s2 = csr[p+2], s3 = csr[p+3];
            uint4 k0 = hrec[s0];
            uint4 k1 = hrec[s1];
            uint4 k2 = hrec[s2];
            uint4 k3 = hrec[s3];
            edge_acc(k0, hdv, alr, acc, den);
            edge_acc(k1, hdv, alr, acc, den);
            edge_acc(k2, hdv, alr, acc, den);
            edge_acc(k3, hdv, alr, acc, den);
        }
        for (; p < lh.y; ++p){
            int s = csr[p];
            uint4 pk = hrec[s];
            edge_acc(pk, hdv, alr, acc, den);
        }
        float inv = 1.f / (den + 1e-16f);
        #pragma unroll
        for (int j = 0; j < 8; j++) o[j] = acc[j]*inv;
        act[i] = pack8(o);
    }
    // BN stats partials (sum, sumsq per channel)
    float v[16];
    #pragma unroll
    for (int j=0;j<8;j++){ v[j]=o[j]; v[8+j]=o[j]*o[j]; }
    #pragma unroll
    for (int off=32; off>0; off>>=1){
        #pragma unroll
        for (int j=0;j<16;j++) v[j] += __shfl_down(v[j], off, 64);
    }
    __shared__ float sred[8][16];
    int lane = t & 63, wv = t >> 6;
    if (lane == 0){
        #pragma unroll
        for (int j=0;j<16;j++) sred[wv][j] = v[j];
    }
    __syncthreads();
    if (t < 16){
        float tot = 0.f;
        #pragma unroll
        for (int w=0; w<8; w++) tot += sred[w][t];
        partials[(size_t)blockIdx.x*16 + t] = tot;
    }
}

__global__ void k_statreduce(const float* __restrict__ partials, float* __restrict__ stats, int nb){
    __shared__ float s[256];
    int t = threadIdx.x;
    int col = t & 15, rg = t >> 4;
    float acc = 0.f;
    for (int r = rg; r < nb; r += 16) acc += partials[(size_t)r*16 + col];
    s[t] = acc; __syncthreads();
    if (t < 16){
        float tot = 0.f;
        #pragma unroll
        for (int k=0;k<16;k++) tot += s[k*16 + t];
        stats[t] = tot;
    }
}

// ---------------- JK-cat (BN+PReLU fused) @ Wjk + bjk, pooled per graph ----------------
static __device__ __forceinline__ int lowerb(const int* __restrict__ a, int n, int key){
    int lo = 0, hi = n;
    while (lo < hi){ int mid = (lo + hi) >> 1; if (a[mid] < key) lo = mid + 1; else hi = mid; }
    return lo;
}

__global__ __launch_bounds__(256) void k_jkpool(
        const uint4* __restrict__ a1, const uint4* __restrict__ a2, const uint4* __restrict__ a3,
        const float* __restrict__ st1, const float* __restrict__ st2, const float* __restrict__ st3,
        const void* __restrict__ g1, const void* __restrict__ be1,
        const void* __restrict__ g2, const void* __restrict__ be2,
        const void* __restrict__ g3, const void* __restrict__ be3,
        const void* __restrict__ alpha,
        const void* __restrict__ Wjk, const void* __restrict__ bjk,
        const int* __restrict__ dflag,
        const int* __restrict__ batch, float* __restrict__ pooled, int n){
    const bool f32 = dflag[0] != 0;
    __shared__ float Wl[192], bl[8], scl[24], sft[24], alv;
    __shared__ int rng[2];
    int t = threadIdx.x, g = blockIdx.x;
    if (t < 192) Wl[t] = ldf(Wjk, t, f32);
    if (t < 8)   bl[t] = ldf(bjk, t, f32);
    if (t < 24){
        int L = t >> 3, j = t & 7;
        const float* st = (L==0)? st1 : (L==1)? st2 : st3;
        const void* gg  = (L==0)? g1  : (L==1)? g2  : g3;
        const void* bb_ = (L==0)? be1 : (L==1)? be2 : be3;
        float invN = 1.f/(float)n;
        float mu  = st[j]*invN;
        float var = fmaxf(st[8+j]*invN - mu*mu, 0.f);
        float s   = ldf(gg, j, f32)*rsqrtf(var + EPSBN);
        scl[t] = s; sft[t] = ldf(bb_, j, f32) - mu*s;
    }
    if (t == 30) alv = ldf(alpha, 0, f32);
    if (t == 0) rng[0] = lowerb(batch, n, g);
    if (t == 1) rng[1] = lowerb(batch, n, g+1);
    __syncthreads();
    int lo = rng[0], hi = rng[1];
    float pa[8] = {0,0,0,0,0,0,0,0};
    for (int i = lo + t; i < hi; i += 256){
        float c[24];
        unpack8(a1[i], c);
        unpack8(a2[i], c+8);
        unpack8(a3[i], c+16);
        #pragma unroll
        for (int k=0;k<24;k++){
            float y = c[k]*scl[k] + sft[k];
            c[k] = (y > 0.f) ? y : alv*y;
        }
        #pragma unroll
        for (int j=0;j<8;j++){
            float acc = bl[j];
            #pragma unroll
            for (int k=0;k<24;k++) acc += c[k]*Wl[k*8+j];
            pa[j] += acc;
        }
    }
    #pragma unroll
    for (int off=32; off>0; off>>=1){
        #pragma unroll
        for (int j=0;j<8;j++) pa[j] += __shfl_down(pa[j], off, 64);
    }
    __shared__ float sr[4][8];
    int lane = t & 63, wv = t >> 6;
    if (lane == 0){
        #pragma unroll
        for (int j=0;j<8;j++) sr[wv][j] = pa[j];
    }
    __syncthreads();
    if (t < 8){
        float tot = sr[0][t]+sr[1][t]+sr[2][t]+sr[3][t];
        pooled[(size_t)g*8 + t] = tot;
    }
}

// ---------------- MLP head ----------------
__global__ __launch_bounds__(1024) void k_final(
        const float* __restrict__ pooled,
        const void* __restrict__ Wm1, const void* __restrict__ bm1,
        const void* __restrict__ gm, const void* __restrict__ bem,
        const void* __restrict__ am,
        const void* __restrict__ Wm2, const void* __restrict__ bm2,
        const int* __restrict__ dflag,
        float* __restrict__ out, int G){
    const bool f32 = dflag[0] != 0;
    int t = threadIdx.x;
    float tv[8] = {0,0,0,0,0,0,0,0};
    if (t < G){
        float r[8];
        #pragma unroll
        for (int j=0;j<8;j++) r[j] = pooled[(size_t)t*8+j];
        #pragma unroll
        for (int j=0;j<8;j++){
            float acc = ldf(bm1, j, f32);
            #pragma unroll
            for (int k=0;k<8;k++) acc += r[k]*ldf(Wm1, k*8+j, f32);
            tv[j] = acc;
        }
    }
    float v[16];
    #pragma unroll
    for (int j=0;j<8;j++){ v[j]=tv[j]; v[8+j]=tv[j]*tv[j]; }
    #pragma unroll
    for (int off=32; off>0; off>>=1){
        #pragma unroll
        for (int j=0;j<16;j++) v[j] += __shfl_down(v[j], off, 64);
    }
    __shared__ float sred[16][16];
    int lane = t & 63, wv = t >> 6;
    if (lane == 0){
        #pragma unroll
        for (int j=0;j<16;j++) sred[wv][j] = v[j];
    }
    __syncthreads();
    __shared__ float stt[16];
    if (t < 16){
        float tot = 0.f;
        #pragma unroll
        for (int w=0; w<16; w++) tot += sred[w][t];
        stt[t] = tot;
    }
    __syncthreads();
    if (t < G){
        float a = ldf(am, 0, f32);
        float invG = 1.f/(float)G;
        float m1[8];
        #pragma unroll
        for (int j=0;j<8;j++){
            float mu  = stt[j]*invG;
            float var = fmaxf(stt[8+j]*invG - mu*mu, 0.f);
            float y = (tv[j]-mu)*rsqrtf(var+EPSBN)*ldf(gm,j,f32)+ldf(bem,j,f32);
            m1[j] = (y>0.f)? y : a*y;
        }
        #pragma unroll
        for (int c=0;c<2;c++){
            float oacc = ldf(bm2, c, f32);
            #pragma unroll
            for (int k=0;k<8;k++) oacc += m1[k]*ldf(Wm2, k*2+c, f32);
            out[(size_t)t*2+c] = oacc;
        }
    }
}

extern "C" void kernel_launch(void* const* d_in, const int* in_sizes, int n_in,
                              void* d_out, int out_size, void* d_ws, size_t ws_size,
                              hipStream_t stream){
    const u16* x16   = (const u16*)d_in[0];
    const void* x    = d_in[0];
    const int* ei    = (const int*)d_in[1];
    const int* batch = (const int*)d_in[2];
    int N = in_sizes[2];
    int E = in_sizes[1] / 2;
    const int* srcA = ei;
    const int* dstA = ei + E;
    const void *W1=d_in[3],  *as1=d_in[4],  *ad1=d_in[5];
    const void *W2=d_in[7],  *as2=d_in[8],  *ad2=d_in[9];
    const void *W3=d_in[11], *as3=d_in[12], *ad3=d_in[13];
    const void *g1=d_in[15], *be1=d_in[16];
    const void *g2=d_in[17], *be2=d_in[18];
    const void *g3=d_in[19], *be3=d_in[20];
    const void *agnn=d_in[21];
    const void *Wjk=d_in[22], *bjk=d_in[23];
    const void *Wm1=d_in[24], *bm1=d_in[25];
    const void *gm =d_in[26], *bem=d_in[27];
    const void *amlp=d_in[28];
    const void *Wm2=d_in[29], *bm2=d_in[30];

    char* p = (char*)d_ws;
    auto carve = [&](size_t bytes) -> void* {
        void* r = (void*)p;
        p += (bytes + 255) & ~(size_t)255;
        return r;
    };
    size_t M = (size_t)E + (size_t)N;
    int nb512 = (N + 511)/512;
    int B  = (N + NPB - 1) / NPB;
    int NC = (E + CHUNK - 1) / CHUNK;          // <= 512
    int*   dflag  = (int*)  carve(256);
    int2*  rowSE  = (int2*) carve((size_t)N*8);
    int*   bb     = (int*)  carve(((size_t)B+1)*4);
    int*   matL   = (int*)  carve((size_t)NC*(B+1)*4);
    int*   matT   = (int*)  carve((size_t)(B+1)*NC*4);
    u32*   stage  = (u32*)  carve((size_t)NC*CHUNK*4);
    int*   csr    = (int*)  carve(M*4);
    uint4* hrec   = (uint4*)carve((size_t)N*16);
    float* hd     = (float*)carve((size_t)N*4);
    uint4* act1   = (uint4*)carve((size_t)N*16);
    uint4* act2   = (uint4*)carve((size_t)N*16);
    uint4* act3   = (uint4*)carve((size_t)N*16);
    float* parts  = (float*)carve((size_t)nb512*64);
    float* stats1 = (float*)carve(64);
    float* stats2 = (float*)carve(64);
    float* stats3 = (float*)carve(64);
    float* pooled = (float*)carve((size_t)NGRAPH*32);
    (void)ws_size; (void)n_in;

    k_sniff<<<1, 64, 0, stream>>>(x16, dflag);

    // ---- atomic-free radix CSR build ----
    k_binsort  <<<NC, 1024, 0, stream>>>(srcA, dstA, stage, matL, E, B);
    {
        dim3 tg(((B+1) + 31)/32, (NC + 31)/32);
        k_mtrans<<<tg, 256, 0, stream>>>(matL, matT, B+1, NC);
    }
    k_bucketsum<<<B, 256, 0, stream>>>(matT, bb, B, NC);
    k_bktbase  <<<1, 1024, 0, stream>>>(bb, B);
    k_bucket   <<<B, 512, 0, stream>>>(stage, matT, bb, rowSE, csr, N, B, NC);

    // layer 1
    k_transform <<<nb512, 512, 0, stream>>>(nullptr, x, dflag, 7, W1, ad1,
                                            nullptr, nullptr, nullptr, agnn, hrec, hd, N);
    k_aggregate <<<nb512, 512, 0, stream>>>(rowSE, csr, hrec, hd, as1, dflag, act1, parts, N);
    k_statreduce<<<1, 256, 0, stream>>>(parts, stats1, nb512);
    // layer 2 (BN1+PReLU fused into transform)
    k_transform <<<nb512, 512, 0, stream>>>(act1, nullptr, dflag, 8, W2, ad2,
                                            stats1, g1, be1, agnn, hrec, hd, N);
    k_aggregate <<<nb512, 512, 0, stream>>>(rowSE, csr, hrec, hd, as2, dflag, act2, parts, N);
    k_statreduce<<<1, 256, 0, stream>>>(parts, stats2, nb512);
    // layer 3
    k_transform <<<nb512, 512, 0, stream>>>(act2, nullptr, dflag, 8, W3, ad3,
                                            stats2, g2, be2, agnn, hrec, hd, N);
    k_aggregate <<<nb512, 512, 0, stream>>>(rowSE, csr, hrec, hd, as3, dflag, act3, parts, N);
    k_statreduce<<<1, 256, 0, stream>>>(parts, stats3, nb512);

    // JK (BN+PReLU fused) + pool + head
    k_jkpool<<<NGRAPH, 256, 0, stream>>>(act1, act2, act3, stats1, stats2, stats3,
                                         g1, be1, g2, be2, g3, be3, agnn,
                                         Wjk, bjk, dflag, batch, pooled, N);
    int G = out_size / 2;
    k_final <<<1, 1024, 0, stream>>>(pooled, Wm1, bm1, gm, bem, amlp, Wm2, bm2, dflag, (float*)d_out, G);
}